// Round 4
// baseline (1395.726 us; speedup 1.0000x reference)
//
#include <hip/hip_runtime.h>
#include <hip/hip_bf16.h>
#include <stdint.h>

#define E_SZ 300
#define H_SZ 512
#define O_SZ 5
#define B_SZ 256
#define T_SZ 200
#define PAD_IDX 1

#define KH 512
#define KE 320            // padded e-width (300 -> 320)
#define KTOT 832          // 512 + 320
#define XS_W 812          // E + H, original weight row width
#define NK 26             // K-steps of 32 (16 h + 10 e)
#define NKH 16
#define NKE 10

#define NRG 8             // row groups (batch split)
#define ROWS 32           // batch rows per WG
#define NSPLIT 32         // n splits per row group
#define NW 16             // n columns per WG per gate
#define WGS 256
#define THREADS 512

#define HROW_PAD 520      // padded LDS row in bf16 elems (1040 B)
#define HROW_B 1040
#define BUF_DW (B_SZ * H_SZ)   // dwords per tagged-h buffer

typedef __bf16  bf16x8 __attribute__((ext_vector_type(8)));
typedef float   f32x4  __attribute__((ext_vector_type(4)));

__device__ __forceinline__ float fsig(float x) { return 1.0f / (1.0f + __expf(-x)); }
__device__ __forceinline__ float ftanh_(float x) {
    float ax = fabsf(x);
    float e  = __expf(-2.0f * ax);
    float r  = (1.0f - e) / (1.0f + e);
    return x < 0.0f ? -r : r;
}

// ---------------- setup kernels ----------------

__global__ void k_pack(const float* __restrict__ Wi, const float* __restrict__ Wf,
                       const float* __restrict__ Wg, const float* __restrict__ Wo,
                       __hip_bfloat16* __restrict__ Wp) {
    int idx = blockIdx.x * blockDim.x + threadIdx.x;
    int total = 4 * H_SZ * KTOT;
    for (int i = idx; i < total; i += gridDim.x * blockDim.x) {
        int k  = i % KTOT;
        int gn = i / KTOT;
        int g = gn >> 9, n = gn & 511;
        const float* W = (g == 0) ? Wi : (g == 1) ? Wf : (g == 2) ? Wg : Wo;
        float v = 0.0f;
        if (k < KH) v = W[n * XS_W + k];
        else { int e = k - KH; if (e < E_SZ) v = W[n * XS_W + KH + e]; }
        Wp[(size_t)gn * KTOT + k] = __float2bfloat16(v);
    }
}

__global__ void k_gather(const int* __restrict__ x, const float* __restrict__ embed,
                         __hip_bfloat16* __restrict__ ebf) {
    int cid = blockIdx.x * blockDim.x + threadIdx.x;   // chunk of 8 elems
    const int nch = T_SZ * B_SZ * (KE / 8);
    if (cid >= nch) return;
    int ch = cid % (KE / 8);
    int tb = cid / (KE / 8);
    int b = tb % B_SZ;
    int t = tb / B_SZ;
    int row = x[b * T_SZ + t];
    const float* er = embed + (size_t)row * E_SZ;
    __hip_bfloat16 v[8];
    int e0 = ch * 8;
#pragma unroll
    for (int j = 0; j < 8; ++j) {
        int e = e0 + j;
        float f = (e < E_SZ) ? er[e] : 0.0f;
        v[j] = __float2bfloat16(f);
    }
    *reinterpret_cast<ulonglong2*>(ebf + ((size_t)t * B_SZ + b) * KE + e0) =
        *reinterpret_cast<const ulonglong2*>(v);
}

// zero final_h, init tagged-h buffers (tag 0xFFFF never matches 1..200), tcap
__global__ void k_misc(const int* __restrict__ x, float* __restrict__ final_h,
                       int* __restrict__ tcap, uint32_t* __restrict__ tagh) {
    int tid = blockIdx.x * blockDim.x + threadIdx.x;
    int n = gridDim.x * blockDim.x;
    for (int i = tid; i < B_SZ * H_SZ; i += n) final_h[i] = 0.0f;
    for (int i = tid; i < 2 * BUF_DW; i += n) tagh[i] = 0xFFFF0000u;
    if (tid < B_SZ) {
        int len = 0;
        for (int t = 0; t < T_SZ; ++t) len += (x[tid * T_SZ + t] != PAD_IDX);
        int tf = (len > 0) ? (len - 1) : 0;
        tcap[tid] = (x[tid * T_SZ + tf] == PAD_IDX) ? -1 : tf;
    }
}

// ---------------- recurrent cooperative kernel ----------------
// 256 WGs x 512 thr. WG (rg=wg&7, ns=wg>>3): rows rg*32..+31, cols ns*16..+15 x4
// gates. Wave w: gate w&3, row-half w>>2. h exchange: self-validating dwords
// {tag=t : h bf16} via relaxed agent-scope atomics. NO barriers, NO fences.
// Poll-on-full-rows guarantees intra-WG ordering: a wave's poll at step t
// requires its own WG's producers' stores of t-1, which sit after sync2(t-1),
// which requires all h_lds readers of t-1 done -> staging writes are safe.
__global__ void __launch_bounds__(THREADS, 2)
k_lstm(const __hip_bfloat16* __restrict__ Wp, const __hip_bfloat16* __restrict__ ebf,
       const float* __restrict__ bi, const float* __restrict__ bfv,
       const float* __restrict__ bg, const float* __restrict__ bo,
       uint32_t* __restrict__ tagh, float* __restrict__ final_h,
       const int* __restrict__ tcap) {
    __shared__ __align__(16) __hip_bfloat16 h_lds[ROWS * HROW_PAD];  // 33,280 B
    __shared__ float pre_lds[4][ROWS][NW + 1];                       //  8,704 B

    const int wg   = blockIdx.x;
    const int rg   = wg & 7;
    const int ns   = wg >> 3;
    const int b0   = rg * ROWS;
    const int n0   = ns * NW;
    const int tid  = threadIdx.x;
    const int wave = tid >> 6;
    const int lane = tid & 63;
    const int l15  = lane & 15;
    const int l4   = lane >> 4;
    const int g    = wave & 3;   // gate
    const int rh   = wave >> 2;  // row half

    // ---- weights: preload (compiler may rematerialize under VGPR cap) ----
    bf16x8 wreg[NK];
    {
        const __hip_bfloat16* wB =
            Wp + ((size_t)(g * H_SZ + n0 + l15)) * KTOT + l4 * 8;
#pragma unroll
        for (int kk = 0; kk < NK; ++kk)
            wreg[kk] = *reinterpret_cast<const bf16x8*>(wB + kk * 32);
    }

    // elementwise constants (threads 0..255: row er, col pair ec/ec+1)
    const int er  = tid >> 3;
    const int ec  = (tid & 7) * 2;
    const int enn = n0 + ec;
    const int ebb = b0 + er;
    float c0r = 0.f, c1r = 0.f;
    float bi0 = 0, bf0 = 0, bg0 = 0, bo0 = 0, bi1 = 0, bf1 = 0, bg1 = 0, bo1 = 0;
    int tc = -2;
    if (tid < 256) {
        bi0 = bi[enn];     bf0 = bfv[enn];     bg0 = bg[enn];     bo0 = bo[enn];
        bi1 = bi[enn + 1]; bf1 = bfv[enn + 1]; bg1 = bg[enn + 1]; bo1 = bo[enn + 1];
        tc = tcap[ebb];
    }

    // consumer geometry: wave stages rows (b0 + wave*4 + k), k=0..3; per row,
    // chunk c=0..3 of 128 dwords; lane covers qword (dwords 128c+2*lane,+1).
    // producer store address (tid<256): qword at dword col enn (even).
    uint64_t* const prod_q =
        (uint64_t*)(tagh) + ((size_t)ebb * H_SZ + enn) / 2;

#pragma unroll 1
    for (int t = 0; t < T_SZ; ++t) {
        f32x4 acc0 = {0.f, 0.f, 0.f, 0.f};
        f32x4 acc1 = {0.f, 0.f, 0.f, 0.f};
        uint64_t q[16];
        const uint64_t* qbase = nullptr;
        if (t > 0) {
            qbase = (const uint64_t*)(tagh + (size_t)((t - 1) & 1) * BUF_DW) +
                    ((size_t)(b0 + wave * 4) * H_SZ) / 2 + lane;
            // issue poll loads; flight overlaps the e-MFMA loop below
#pragma unroll
            for (int k = 0; k < 4; ++k)
#pragma unroll
                for (int c = 0; c < 4; ++c)
                    q[k * 4 + c] = __hip_atomic_load(
                        qbase + (size_t)k * (H_SZ / 2) + c * 64,
                        __ATOMIC_RELAXED, __HIP_MEMORY_SCOPE_AGENT);
        }
        // e-part MFMAs (cached loads)
        const __hip_bfloat16* ea =
            ebf + ((size_t)t * B_SZ + b0 + rh * 16 + l15) * KE + l4 * 8;
#pragma unroll
        for (int kk = 0; kk < NKE; ++kk) {
            bf16x8 a = *reinterpret_cast<const bf16x8*>(ea + kk * 32);
            if (kk & 1) acc1 = __builtin_amdgcn_mfma_f32_16x16x32_bf16(a, wreg[NKH + kk], acc1, 0, 0, 0);
            else        acc0 = __builtin_amdgcn_mfma_f32_16x16x32_bf16(a, wreg[NKH + kk], acc0, 0, 0, 0);
        }
        if (t > 0) {
            const uint32_t pat = ((uint32_t)t) << 16;   // expected tag in hi16
            for (;;) {
                uint32_t bad = 0;
#pragma unroll
                for (int j = 0; j < 16; ++j) {
                    bad |= ((uint32_t)q[j] ^ pat);
                    bad |= ((uint32_t)(q[j] >> 32) ^ pat);
                }
                if (__all((bad >> 16) == 0u)) break;
                __builtin_amdgcn_s_sleep(2);
#pragma unroll
                for (int k = 0; k < 4; ++k)
#pragma unroll
                    for (int c = 0; c < 4; ++c)
                        q[k * 4 + c] = __hip_atomic_load(
                            qbase + (size_t)k * (H_SZ / 2) + c * 64,
                            __ATOMIC_RELAXED, __HIP_MEMORY_SCOPE_AGENT);
            }
            // strip tags (v_perm) and stage: dword col 128c+2*lane of row k
            // -> h_lds byte (wave*4+k)*HROW_B + c*256 + lane*4 (2 lanes/bank)
#pragma unroll
            for (int k = 0; k < 4; ++k) {
                uint32_t* lrow = (uint32_t*)((char*)(&h_lds[0]) +
                                             (wave * 4 + k) * HROW_B);
#pragma unroll
                for (int c = 0; c < 4; ++c) {
                    uint64_t v = q[k * 4 + c];
                    lrow[c * 64 + lane] = __builtin_amdgcn_perm(
                        (uint32_t)(v >> 32), (uint32_t)v, 0x05040100u);
                }
            }
            __syncthreads();
            // h-part MFMAs from LDS
            const char* hl_a = (const char*)(&h_lds[0]) +
                               (rh * 16 + l15) * HROW_B + l4 * 16;
#pragma unroll
            for (int kk = 0; kk < NKH; ++kk) {
                bf16x8 a = *reinterpret_cast<const bf16x8*>(hl_a + kk * 64);
                if (kk & 1) acc1 = __builtin_amdgcn_mfma_f32_16x16x32_bf16(a, wreg[kk], acc1, 0, 0, 0);
                else        acc0 = __builtin_amdgcn_mfma_f32_16x16x32_bf16(a, wreg[kk], acc0, 0, 0, 0);
            }
        }
        f32x4 acc = acc0 + acc1;
        // scatter pre-activations (C/D: row=(lane>>4)*4+j, col=lane&15)
#pragma unroll
        for (int j = 0; j < 4; ++j)
            pre_lds[g][rh * 16 + l4 * 4 + j][l15] = acc[j];
        __syncthreads();
        // elementwise (threads 0..255, 2 cols each) + tagged h store
        if (tid < 256) {
            float pi0 = pre_lds[0][er][ec]     + bi0;
            float pf_ = pre_lds[1][er][ec]     + bf0;
            float pg0 = pre_lds[2][er][ec]     + bg0;
            float po0 = pre_lds[3][er][ec]     + bo0;
            float pi1 = pre_lds[0][er][ec + 1] + bi1;
            float pf1 = pre_lds[1][er][ec + 1] + bf1;
            float pg1 = pre_lds[2][er][ec + 1] + bg1;
            float po1 = pre_lds[3][er][ec + 1] + bo1;
            float i0 = fsig(pi0), f0 = fsig(pf_), g0v = ftanh_(pg0), o0 = fsig(po0);
            float i1 = fsig(pi1), f1 = fsig(pf1), g1v = ftanh_(pg1), o1 = fsig(po1);
            c0r = f0 * c0r + i0 * g0v;
            c1r = f1 * c1r + i1 * g1v;
            float h0 = ftanh_(c0r) * o0;
            float h1 = ftanh_(c1r) * o1;
            const uint32_t pat_s = ((uint32_t)(t + 1)) << 16;
            uint32_t lo = (uint32_t)__builtin_bit_cast(uint16_t, __float2bfloat16(h0)) | pat_s;
            uint32_t hi = (uint32_t)__builtin_bit_cast(uint16_t, __float2bfloat16(h1)) | pat_s;
            uint64_t pk = (uint64_t)lo | ((uint64_t)hi << 32);
            __hip_atomic_store(prod_q + (size_t)(t & 1) * (BUF_DW / 2), pk,
                               __ATOMIC_RELAXED, __HIP_MEMORY_SCOPE_AGENT);
            if (t == tc) {
                final_h[(size_t)ebb * H_SZ + enn]     = h0;
                final_h[(size_t)ebb * H_SZ + enn + 1] = h1;
            }
        }
        // no end-of-step barrier: tags carry the synchronization
    }
}

// ---------------- output head ----------------
__global__ void k_out(const float* __restrict__ fin, const float* __restrict__ Wout,
                      const float* __restrict__ bout, float* __restrict__ out) {
    int b = blockIdx.x;
    int lane = threadIdx.x;  // 64
    float s0 = 0, s1 = 0, s2 = 0, s3 = 0, s4 = 0;
    const float* fr = fin + (size_t)b * H_SZ;
    for (int n = lane; n < H_SZ; n += 64) {
        float h = fr[n];
        s0 += h * Wout[0 * H_SZ + n];
        s1 += h * Wout[1 * H_SZ + n];
        s2 += h * Wout[2 * H_SZ + n];
        s3 += h * Wout[3 * H_SZ + n];
        s4 += h * Wout[4 * H_SZ + n];
    }
#pragma unroll
    for (int off = 32; off >= 1; off >>= 1) {
        s0 += __shfl_down(s0, off);
        s1 += __shfl_down(s1, off);
        s2 += __shfl_down(s2, off);
        s3 += __shfl_down(s3, off);
        s4 += __shfl_down(s4, off);
    }
    if (lane == 0) {
        out[b * O_SZ + 0] = s0 + bout[0];
        out[b * O_SZ + 1] = s1 + bout[1];
        out[b * O_SZ + 2] = s2 + bout[2];
        out[b * O_SZ + 3] = s3 + bout[3];
        out[b * O_SZ + 4] = s4 + bout[4];
    }
}

// ---------------- launch ----------------
extern "C" void kernel_launch(void* const* d_in, const int* in_sizes, int n_in,
                              void* d_out, int out_size, void* d_ws, size_t ws_size,
                              hipStream_t stream) {
    const int*   x     = (const int*)d_in[0];
    const float* embed = (const float*)d_in[1];
    const float* Wi    = (const float*)d_in[2];
    const float* bi    = (const float*)d_in[3];
    const float* Wf    = (const float*)d_in[4];
    const float* bfv   = (const float*)d_in[5];
    const float* Wg    = (const float*)d_in[6];
    const float* bg    = (const float*)d_in[7];
    const float* Wo    = (const float*)d_in[8];
    const float* bo    = (const float*)d_in[9];
    const float* Wout  = (const float*)d_in[10];
    const float* bout  = (const float*)d_in[11];
    float* out = (float*)d_out;

    char* ws = (char*)d_ws;
    size_t off = 0;
    auto alloc = [&](size_t bytes) {
        void* p = ws + off;
        off = (off + bytes + 255) & ~(size_t)255;
        return p;
    };
    __hip_bfloat16* Wp  = (__hip_bfloat16*)alloc((size_t)4 * H_SZ * KTOT * 2);
    __hip_bfloat16* ebf = (__hip_bfloat16*)alloc((size_t)T_SZ * B_SZ * KE * 2);
    uint32_t* tagh      = (uint32_t*)alloc((size_t)2 * BUF_DW * 4);
    float* finh         = (float*)alloc((size_t)B_SZ * H_SZ * 4);
    int*   tcap         = (int*)alloc((size_t)B_SZ * 4);
    (void)ws_size; (void)in_sizes; (void)n_in; (void)out_size;

    k_pack<<<832, 256, 0, stream>>>(Wi, Wf, Wg, Wo, Wp);
    k_gather<<<(T_SZ * B_SZ * (KE / 8) + 255) / 256, 256, 0, stream>>>(x, embed, ebf);
    k_misc<<<128, 256, 0, stream>>>(x, finh, tcap, tagh);

    void* args[] = { &Wp, &ebf, &bi, &bfv, &bg, &bo, &tagh, &finh, &tcap };
    hipLaunchCooperativeKernel((void*)k_lstm, dim3(WGS), dim3(THREADS), args, 0, stream);

    k_out<<<B_SZ, 64, 0, stream>>>(finh, Wout, bout, out);
}

// Round 5
// 877.881 us; speedup vs baseline: 1.5899x; 1.5899x over previous
//
#include <hip/hip_runtime.h>
#include <hip/hip_bf16.h>
#include <stdint.h>

#define E_SZ 300
#define H_SZ 512
#define O_SZ 5
#define B_SZ 256
#define T_SZ 200
#define PAD_IDX 1

#define KH 512
#define KE 320            // padded e-width (300 -> 320)
#define KTOT 832          // 512 + 320
#define XS_W 812          // E + H, original weight row width
#define NK 26             // K-steps of 32 (16 h + 10 e)
#define NKH 16
#define NKE 10

#define NRG 8             // row groups (batch split)
#define ROWS 32           // batch rows per WG
#define NSPLIT 32         // n splits per row group
#define NW 16             // n columns per WG per gate
#define WGS 256
#define THREADS 512

#define HROW_PAD 520      // padded LDS row in bf16 elems (1040 B)
#define HROW_B 1040
#define HBUF_HALF (B_SZ * H_SZ)   // bf16 elems per h buffer

typedef __bf16  bf16x8 __attribute__((ext_vector_type(8)));
typedef float   f32x4  __attribute__((ext_vector_type(4)));
typedef uint32_t u32x4 __attribute__((ext_vector_type(4)));

__device__ __forceinline__ float fsig(float x) { return 1.0f / (1.0f + __expf(-x)); }
__device__ __forceinline__ float ftanh_(float x) {
    float ax = fabsf(x);
    float e  = __expf(-2.0f * ax);
    float r  = (1.0f - e) / (1.0f + e);
    return x < 0.0f ? -r : r;
}

// ---------------- setup kernels ----------------

__global__ void k_pack(const float* __restrict__ Wi, const float* __restrict__ Wf,
                       const float* __restrict__ Wg, const float* __restrict__ Wo,
                       __hip_bfloat16* __restrict__ Wp) {
    int idx = blockIdx.x * blockDim.x + threadIdx.x;
    int total = 4 * H_SZ * KTOT;
    for (int i = idx; i < total; i += gridDim.x * blockDim.x) {
        int k  = i % KTOT;
        int gn = i / KTOT;
        int g = gn >> 9, n = gn & 511;
        const float* W = (g == 0) ? Wi : (g == 1) ? Wf : (g == 2) ? Wg : Wo;
        float v = 0.0f;
        if (k < KH) v = W[n * XS_W + k];
        else { int e = k - KH; if (e < E_SZ) v = W[n * XS_W + KH + e]; }
        Wp[(size_t)gn * KTOT + k] = __float2bfloat16(v);
    }
}

__global__ void k_gather(const int* __restrict__ x, const float* __restrict__ embed,
                         __hip_bfloat16* __restrict__ ebf) {
    int cid = blockIdx.x * blockDim.x + threadIdx.x;   // chunk of 8 elems
    const int nch = T_SZ * B_SZ * (KE / 8);
    if (cid >= nch) return;
    int ch = cid % (KE / 8);
    int tb = cid / (KE / 8);
    int b = tb % B_SZ;
    int t = tb / B_SZ;
    int row = x[b * T_SZ + t];
    const float* er = embed + (size_t)row * E_SZ;
    __hip_bfloat16 v[8];
    int e0 = ch * 8;
#pragma unroll
    for (int j = 0; j < 8; ++j) {
        int e = e0 + j;
        float f = (e < E_SZ) ? er[e] : 0.0f;
        v[j] = __float2bfloat16(f);
    }
    *reinterpret_cast<ulonglong2*>(ebf + ((size_t)t * B_SZ + b) * KE + e0) =
        *reinterpret_cast<const ulonglong2*>(v);
}

// zero final_h, flags, census; compute capture step per row
__global__ void k_misc(const int* __restrict__ x, float* __restrict__ final_h,
                       int* __restrict__ tcap, int* __restrict__ flags,
                       int* __restrict__ cns) {
    int tid = blockIdx.x * blockDim.x + threadIdx.x;
    int n = gridDim.x * blockDim.x;
    for (int i = tid; i < B_SZ * H_SZ; i += n) final_h[i] = 0.0f;
    if (tid < NRG * NSPLIT) flags[tid] = 0;
    if (tid < 16) cns[tid] = 0;
    if (tid < B_SZ) {
        int len = 0;
        for (int t = 0; t < T_SZ; ++t) len += (x[tid * T_SZ + t] != PAD_IDX);
        int tf = (len > 0) ? (len - 1) : 0;
        tcap[tid] = (x[tid * T_SZ + tf] == PAD_IDX) ? -1 : tf;
    }
}

// ---------------- recurrent cooperative kernel ----------------
// 256 WGs x 512 thr. Placement census: if each XCD hosts exactly 32 WGs,
// row group := measured XCD id, ns := arrival ticket -> h exchange is
// XCD-L2-local (plain stores + sc0 polls/loads). Else: agent-scope atomics
// (fabric) fallback. Correctness independent of placement (G16).
// Protocol per step t: producers store plain/agent h dwords into hbuf[t&1],
// __syncthreads (acks), one flag=t+1 per WG. Consumers poll 32 flags >= t,
// bulk-read 32 rows once, stage to LDS, h-MFMA. Monotonic flags; 2-buffer
// WAR-safe (store t+1 requires poll >= t which requires all reads of t-1).
__global__ void __launch_bounds__(THREADS, 2)
k_lstm(const __hip_bfloat16* __restrict__ Wp, const __hip_bfloat16* __restrict__ ebf,
       const float* __restrict__ bi, const float* __restrict__ bfv,
       const float* __restrict__ bg, const float* __restrict__ bo,
       __hip_bfloat16* __restrict__ hbuf, float* __restrict__ final_h,
       const int* __restrict__ tcap, int* __restrict__ flags,
       int* __restrict__ cns) {
    __shared__ __align__(16) __hip_bfloat16 h_lds[ROWS * HROW_PAD];  // 33,280 B
    __shared__ float pre_lds[4][ROWS][NW + 1];                       //  8,704 B
    __shared__ int s_meta[3];

    const int tid  = threadIdx.x;
    const int wave = tid >> 6;
    const int lane = tid & 63;
    const int l15  = lane & 15;
    const int l4   = lane >> 4;
    const int g    = wave & 3;   // gate
    const int rh   = wave >> 2;  // row half

    // ---- placement census (once) ----
    if (tid == 0) {
        uint32_t xcc;
        asm volatile("s_getreg_b32 %0, hwreg(HW_REG_XCC_ID)" : "=s"(xcc));
        xcc &= 7;
        int ticket = __hip_atomic_fetch_add(&cns[xcc], 1, __ATOMIC_RELAXED,
                                            __HIP_MEMORY_SCOPE_AGENT);
        __hip_atomic_fetch_add(&cns[8], 1, __ATOMIC_RELEASE,
                               __HIP_MEMORY_SCOPE_AGENT);
        while (__hip_atomic_load(&cns[8], __ATOMIC_RELAXED,
                                 __HIP_MEMORY_SCOPE_AGENT) < WGS)
            __builtin_amdgcn_s_sleep(8);
        (void)__hip_atomic_load(&cns[8], __ATOMIC_ACQUIRE,
                                __HIP_MEMORY_SCOPE_AGENT);
        int bal = 1;
        for (int i = 0; i < 8; ++i)
            bal &= (__hip_atomic_load(&cns[i], __ATOMIC_RELAXED,
                                      __HIP_MEMORY_SCOPE_AGENT) == NSPLIT);
        s_meta[0] = bal ? (int)xcc : (int)(blockIdx.x & 7);
        s_meta[1] = bal ? ticket : (int)(blockIdx.x >> 3);
        s_meta[2] = bal;
    }
    __syncthreads();
    const int rg   = s_meta[0];
    const int ns   = s_meta[1];
    const int fast = s_meta[2];
    const int b0   = rg * ROWS;
    const int n0   = ns * NW;

    // ---- weights -> registers ----
    bf16x8 wreg[NK];
    {
        const __hip_bfloat16* wB =
            Wp + ((size_t)(g * H_SZ + n0 + l15)) * KTOT + l4 * 8;
#pragma unroll
        for (int kk = 0; kk < NK; ++kk)
            wreg[kk] = *reinterpret_cast<const bf16x8*>(wB + kk * 32);
    }

    // elementwise constants (threads 0..255: row er, col pair ec/ec+1)
    const int er  = tid >> 3;
    const int ec  = (tid & 7) * 2;
    const int enn = n0 + ec;
    const int ebb = b0 + er;
    float c0r = 0.f, c1r = 0.f;
    float bi0 = 0, bf0 = 0, bg0 = 0, bo0 = 0, bi1 = 0, bf1 = 0, bg1 = 0, bo1 = 0;
    int tc = -2;
    if (tid < 256) {
        bi0 = bi[enn];     bf0 = bfv[enn];     bg0 = bg[enn];     bo0 = bo[enn];
        bi1 = bi[enn + 1]; bf1 = bfv[enn + 1]; bg1 = bg[enn + 1]; bo1 = bo[enn + 1];
        tc = tcap[ebb];
    }

    int* const fpoll = flags + rg * NSPLIT + (lane & 31);
    int* const fmine = flags + rg * NSPLIT + ns;
    char* const lw   = (char*)(&h_lds[0]) + (wave * 4) * HROW_B;
    const char* hl_a = (const char*)(&h_lds[0]) + (rh * 16 + l15) * HROW_B + l4 * 16;

#pragma unroll 1
    for (int t = 0; t < T_SZ; ++t) {
        f32x4 acc0 = {0.f, 0.f, 0.f, 0.f};
        f32x4 acc1 = {0.f, 0.f, 0.f, 0.f};
        // e-part MFMAs (cached loads, L2-warm)
        const __hip_bfloat16* ea =
            ebf + ((size_t)t * B_SZ + b0 + rh * 16 + l15) * KE + l4 * 8;
#pragma unroll
        for (int kk = 0; kk < NKE; ++kk) {
            bf16x8 a = *reinterpret_cast<const bf16x8*>(ea + kk * 32);
            if (kk & 1) acc1 = __builtin_amdgcn_mfma_f32_16x16x32_bf16(a, wreg[NKH + kk], acc1, 0, 0, 0);
            else        acc0 = __builtin_amdgcn_mfma_f32_16x16x32_bf16(a, wreg[NKH + kk], acc0, 0, 0, 0);
        }
        if (t > 0) {
            const uint32_t want = (uint32_t)t;   // flag >= t: step t-1 data ready
            uint32_t fv;
            if (fast) {
                for (;;) {
                    asm volatile("global_load_dword %0, %1, off sc0\n\t"
                                 "s_waitcnt vmcnt(0)"
                                 : "=&v"(fv)
                                 : "v"((uint64_t)(uintptr_t)fpoll) : "memory");
                    if (__all(fv >= want)) break;
                    __builtin_amdgcn_s_sleep(1);
                }
            } else {
                for (;;) {
                    fv = (uint32_t)__hip_atomic_load(fpoll, __ATOMIC_RELAXED,
                                                     __HIP_MEMORY_SCOPE_AGENT);
                    if (__all(fv >= want)) break;
                    __builtin_amdgcn_s_sleep(2);
                }
            }
            // bulk read 4 rows (1 KB each) + stage to LDS
            const char* hb = (const char*)hbuf +
                             (size_t)((t - 1) & 1) * (HBUF_HALF * 2);
            if (fast) {
                u32x4 q0, q1, q2, q3;
                const char* dp = hb + (size_t)(b0 + wave * 4) * 1024 + lane * 16;
                asm volatile(
                    "global_load_dwordx4 %0, %4, off sc0\n\t"
                    "global_load_dwordx4 %1, %4, off offset:1024 sc0\n\t"
                    "global_load_dwordx4 %2, %4, off offset:2048 sc0\n\t"
                    "global_load_dwordx4 %3, %4, off offset:3072 sc0\n\t"
                    "s_waitcnt vmcnt(0)"
                    : "=&v"(q0), "=&v"(q1), "=&v"(q2), "=&v"(q3)
                    : "v"((uint64_t)(uintptr_t)dp) : "memory");
                *reinterpret_cast<u32x4*>(lw + lane * 16)              = q0;
                *reinterpret_cast<u32x4*>(lw + HROW_B + lane * 16)     = q1;
                *reinterpret_cast<u32x4*>(lw + 2 * HROW_B + lane * 16) = q2;
                *reinterpret_cast<u32x4*>(lw + 3 * HROW_B + lane * 16) = q3;
            } else {
                uint32_t dep = fv;
                asm volatile("" : "+v"(dep));           // addr-dependence launder
                const uint64_t* qp =
                    (const uint64_t*)(hb + (size_t)(b0 + wave * 4) * 1024) +
                    lane + (dep >> 16);
#pragma unroll
                for (int k = 0; k < 4; ++k) {
                    uint64_t a = __hip_atomic_load(qp + k * 128, __ATOMIC_RELAXED,
                                                   __HIP_MEMORY_SCOPE_AGENT);
                    uint64_t b = __hip_atomic_load(qp + k * 128 + 64, __ATOMIC_RELAXED,
                                                   __HIP_MEMORY_SCOPE_AGENT);
                    *reinterpret_cast<uint64_t*>(lw + k * HROW_B + lane * 8)       = a;
                    *reinterpret_cast<uint64_t*>(lw + k * HROW_B + 512 + lane * 8) = b;
                }
            }
            __syncthreads();
            // h-part MFMAs from LDS
#pragma unroll
            for (int kk = 0; kk < NKH; ++kk) {
                bf16x8 a = *reinterpret_cast<const bf16x8*>(hl_a + kk * 64);
                if (kk & 1) acc1 = __builtin_amdgcn_mfma_f32_16x16x32_bf16(a, wreg[kk], acc1, 0, 0, 0);
                else        acc0 = __builtin_amdgcn_mfma_f32_16x16x32_bf16(a, wreg[kk], acc0, 0, 0, 0);
            }
        }
        f32x4 acc = acc0 + acc1;
        // scatter pre-activations (C/D: row=(lane>>4)*4+j, col=lane&15)
#pragma unroll
        for (int j = 0; j < 4; ++j)
            pre_lds[g][rh * 16 + l4 * 4 + j][l15] = acc[j];
        __syncthreads();
        // elementwise (threads 0..255, 2 cols each) + h store
        if (tid < 256) {
            float pi0 = pre_lds[0][er][ec]     + bi0;
            float pf_ = pre_lds[1][er][ec]     + bf0;
            float pg0 = pre_lds[2][er][ec]     + bg0;
            float po0 = pre_lds[3][er][ec]     + bo0;
            float pi1 = pre_lds[0][er][ec + 1] + bi1;
            float pf1 = pre_lds[1][er][ec + 1] + bf1;
            float pg1 = pre_lds[2][er][ec + 1] + bg1;
            float po1 = pre_lds[3][er][ec + 1] + bo1;
            float i0 = fsig(pi0), f0 = fsig(pf_), g0v = ftanh_(pg0), o0 = fsig(po0);
            float i1 = fsig(pi1), f1 = fsig(pf1), g1v = ftanh_(pg1), o1 = fsig(po1);
            c0r = f0 * c0r + i0 * g0v;
            c1r = f1 * c1r + i1 * g1v;
            float h0 = ftanh_(c0r) * o0;
            float h1 = ftanh_(c1r) * o1;
            uint32_t pk =
                (uint32_t)__builtin_bit_cast(uint16_t, __float2bfloat16(h0)) |
                ((uint32_t)__builtin_bit_cast(uint16_t, __float2bfloat16(h1)) << 16);
            uint32_t* hw = (uint32_t*)((char*)hbuf +
                           (size_t)(t & 1) * (HBUF_HALF * 2) +
                           ((size_t)ebb * H_SZ + enn) * 2);
            if (fast)
                __hip_atomic_store(hw, pk, __ATOMIC_RELAXED,
                                   __HIP_MEMORY_SCOPE_WORKGROUP);
            else
                __hip_atomic_store(hw, pk, __ATOMIC_RELAXED,
                                   __HIP_MEMORY_SCOPE_AGENT);
            if (t == tc) {
                final_h[(size_t)ebb * H_SZ + enn]     = h0;
                final_h[(size_t)ebb * H_SZ + enn + 1] = h1;
            }
        }
        // ack: all threads' stores complete, then publish flag t+1
        __syncthreads();
        if (tid == 0) {
            if (fast)
                __hip_atomic_store(fmine, t + 1, __ATOMIC_RELAXED,
                                   __HIP_MEMORY_SCOPE_WORKGROUP);
            else
                __hip_atomic_store(fmine, t + 1, __ATOMIC_RELAXED,
                                   __HIP_MEMORY_SCOPE_AGENT);
        }
    }
}

// ---------------- output head ----------------
__global__ void k_out(const float* __restrict__ fin, const float* __restrict__ Wout,
                      const float* __restrict__ bout, float* __restrict__ out) {
    int b = blockIdx.x;
    int lane = threadIdx.x;  // 64
    float s0 = 0, s1 = 0, s2 = 0, s3 = 0, s4 = 0;
    const float* fr = fin + (size_t)b * H_SZ;
    for (int n = lane; n < H_SZ; n += 64) {
        float h = fr[n];
        s0 += h * Wout[0 * H_SZ + n];
        s1 += h * Wout[1 * H_SZ + n];
        s2 += h * Wout[2 * H_SZ + n];
        s3 += h * Wout[3 * H_SZ + n];
        s4 += h * Wout[4 * H_SZ + n];
    }
#pragma unroll
    for (int off = 32; off >= 1; off >>= 1) {
        s0 += __shfl_down(s0, off);
        s1 += __shfl_down(s1, off);
        s2 += __shfl_down(s2, off);
        s3 += __shfl_down(s3, off);
        s4 += __shfl_down(s4, off);
    }
    if (lane == 0) {
        out[b * O_SZ + 0] = s0 + bout[0];
        out[b * O_SZ + 1] = s1 + bout[1];
        out[b * O_SZ + 2] = s2 + bout[2];
        out[b * O_SZ + 3] = s3 + bout[3];
        out[b * O_SZ + 4] = s4 + bout[4];
    }
}

// ---------------- launch ----------------
extern "C" void kernel_launch(void* const* d_in, const int* in_sizes, int n_in,
                              void* d_out, int out_size, void* d_ws, size_t ws_size,
                              hipStream_t stream) {
    const int*   x     = (const int*)d_in[0];
    const float* embed = (const float*)d_in[1];
    const float* Wi    = (const float*)d_in[2];
    const float* bi    = (const float*)d_in[3];
    const float* Wf    = (const float*)d_in[4];
    const float* bfv   = (const float*)d_in[5];
    const float* Wg    = (const float*)d_in[6];
    const float* bg    = (const float*)d_in[7];
    const float* Wo    = (const float*)d_in[8];
    const float* bo    = (const float*)d_in[9];
    const float* Wout  = (const float*)d_in[10];
    const float* bout  = (const float*)d_in[11];
    float* out = (float*)d_out;

    char* ws = (char*)d_ws;
    size_t off = 0;
    auto alloc = [&](size_t bytes) {
        void* p = ws + off;
        off = (off + bytes + 255) & ~(size_t)255;
        return p;
    };
    __hip_bfloat16* Wp   = (__hip_bfloat16*)alloc((size_t)4 * H_SZ * KTOT * 2);
    __hip_bfloat16* ebf  = (__hip_bfloat16*)alloc((size_t)T_SZ * B_SZ * KE * 2);
    __hip_bfloat16* hbuf = (__hip_bfloat16*)alloc((size_t)2 * HBUF_HALF * 2);
    float* finh          = (float*)alloc((size_t)B_SZ * H_SZ * 4);
    int*   tcap          = (int*)alloc((size_t)B_SZ * 4);
    int*   flags         = (int*)alloc((size_t)NRG * NSPLIT * 4);
    int*   cns           = (int*)alloc((size_t)16 * 4);
    (void)ws_size; (void)in_sizes; (void)n_in; (void)out_size;

    k_pack<<<832, 256, 0, stream>>>(Wi, Wf, Wg, Wo, Wp);
    k_gather<<<(T_SZ * B_SZ * (KE / 8) + 255) / 256, 256, 0, stream>>>(x, embed, ebf);
    k_misc<<<128, 256, 0, stream>>>(x, finh, tcap, flags, cns);

    void* args[] = { &Wp, &ebf, &bi, &bfv, &bg, &bo, &hbuf, &finh, &tcap,
                     &flags, &cns };
    hipLaunchCooperativeKernel((void*)k_lstm, dim3(WGS), dim3(THREADS), args, 0, stream);

    k_out<<<B_SZ, 64, 0, stream>>>(finh, Wout, bout, out);
}